// Round 15
// baseline (137.645 us; speedup 1.0000x reference)
//
#include <hip/hip_runtime.h>
#include <math.h>

#define D_MODEL 1024
#define STATE 64
#define HEADS 8
#define INNER 2048
#define HEAD_DIM 256
#define PROJ_OUT 4232   // 2*INNER + 2*STATE + HEADS
#define DT_OFF  4224    // 2*INNER + 2*STATE
#define NPAD 4352       // 34*128
#define BATCH 2
#define SEQ 1024
#define NROWS (BATCH*SEQ)
#define EPS 1e-5f
#define BH (BATCH * HEADS)      // 16
#define LQ 32                   // SSD chunk length
#define NCH (SEQ / LQ)          // 32 chunks

typedef short s16x8 __attribute__((ext_vector_type(8)));
typedef float f32x4 __attribute__((ext_vector_type(4)));

#define LDS_AS(p) ((__attribute__((address_space(3))) void*)(p))
#define GLB_AS(p) ((const __attribute__((address_space(1))) void*)(p))

__device__ inline unsigned short f2bf(float f) {
    unsigned int u = __float_as_uint(f);
    unsigned int r = (u + 0x7fffu + ((u >> 16) & 1u)) >> 16;
    return (unsigned short)r;
}
__device__ inline float bf2f(unsigned short s) {
    return __uint_as_float(((unsigned int)s) << 16);
}
__device__ inline f32x4 mfma16(s16x8 a, s16x8 b, f32x4 c) {
    return __builtin_amdgcn_mfma_f32_16x16x32_bf16(a, b, c, 0, 0, 0);
}

// ====== prep: fused {W_in transpose, W_out transpose, LayerNorm} ======
__global__ __launch_bounds__(256) void prep_kernel(
    const float* __restrict__ x, const float* __restrict__ gamma,
    const float* __restrict__ beta,
    const float* __restrict__ W_in, const float* __restrict__ W_out,
    unsigned short* __restrict__ normed, unsigned short* __restrict__ WT,
    unsigned short* __restrict__ WoT)
{
    constexpr int T1 = (NPAD / 32) * (D_MODEL / 32);   // 4352
    constexpr int T2 = (D_MODEL / 32) * (INNER / 32);  // 2048
    __shared__ float tile[32][33];
    __shared__ float ls[4], lq[4];
    const int bid = blockIdx.x;
    const int tid = threadIdx.x;

    if (bid < T1 + T2) {
        const float* in;
        unsigned short* out;
        int R, C, bx, by;
        if (bid < T1) {
            in = W_in; out = WT; R = D_MODEL; C = PROJ_OUT;
            bx = bid % (NPAD / 32); by = bid / (NPAD / 32);
        } else {
            int t = bid - T1;
            in = W_out; out = WoT; R = INNER; C = D_MODEL;
            bx = t % (D_MODEL / 32); by = t / (D_MODEL / 32);
        }
        int c0 = bx * 32, r0 = by * 32;
        int tx = tid & 31, ty = tid >> 5;
        #pragma unroll
        for (int i = 0; i < 4; ++i) {
            int r = ty + i * 8;
            int gc = c0 + tx;
            tile[r][tx] = (gc < C) ? in[(size_t)(r0 + r) * C + gc] : 0.f;
        }
        __syncthreads();
        #pragma unroll
        for (int i = 0; i < 4; ++i) {
            int oc = ty + i * 8;
            out[(size_t)(c0 + oc) * R + r0 + tx] = f2bf(tile[tx][oc]);
        }
    } else {
        int t = bid - T1 - T2;
        int wave = tid >> 6, lane = tid & 63;
        #pragma unroll
        for (int rr = 0; rr < 2; ++rr) {
            int row = t * 2 + rr;
            const float4* xr = (const float4*)(x + (size_t)row * D_MODEL);
            float4 v = xr[tid];
            float s  = v.x + v.y + v.z + v.w;
            float sq = v.x*v.x + v.y*v.y + v.z*v.z + v.w*v.w;
            #pragma unroll
            for (int off = 32; off > 0; off >>= 1) {
                s  += __shfl_down(s,  off, 64);
                sq += __shfl_down(sq, off, 64);
            }
            if (lane == 0) { ls[wave] = s; lq[wave] = sq; }
            __syncthreads();
            s  = ls[0] + ls[1] + ls[2] + ls[3];
            sq = lq[0] + lq[1] + lq[2] + lq[3];
            float mu  = s * (1.f / D_MODEL);
            float var = sq * (1.f / D_MODEL) - mu * mu;
            float rs  = rsqrtf(var + EPS);
            float4 g  = ((const float4*)gamma)[tid];
            float4 bb = ((const float4*)beta)[tid];
            ushort4 o;
            o.x = f2bf((v.x - mu) * rs * g.x + bb.x);
            o.y = f2bf((v.y - mu) * rs * g.y + bb.y);
            o.z = f2bf((v.z - mu) * rs * g.z + bb.z);
            o.w = f2bf((v.w - mu) * rs * g.w + bb.w);
            ((ushort4*)(normed + (size_t)row * D_MODEL))[tid] = o;
            __syncthreads();
        }
    }
}

// ---- bf16 MFMA GEMM: BK=64, 2-buf dbuf, counted vmcnt, XCD swizzle ----
// Per K-step each wave runs 32 MFMAs (2x the BK=32 version); barrier pairs
// halve; fixed per-iteration cost amortized over 2x compute.
template<int BM, int BN, int RECT_N, int RECT_M, int CHX,
         bool HAS_ADD, bool GUARD_N, bool OUT_BF16>
__global__ __launch_bounds__(256) void gemm_bf16(
    const unsigned short* __restrict__ A, const unsigned short* __restrict__ BT,
    const float* __restrict__ bias, const float* __restrict__ add,
    float* __restrict__ C, unsigned short* __restrict__ Cb,
    float* __restrict__ dtb, int Nreal, int Nstride, int K)
{
    constexpr int FM = BM / 32;          // m-frags per wave (2x2 wave grid)
    constexpr int FN = BN / 32;
    constexpr int MFRAG = BM / 16;       // m-frags per tile
    constexpr int NFRAG = BN / 16;
    constexpr int NL = (BM + BN) / 32;   // loads/thread/stage at BK=64
    __shared__ unsigned short Asm[2][BM * 64];
    __shared__ unsigned short Bsm[2][BN * 64];
    const int tid = threadIdx.x;
    const int l = tid & 63, w = tid >> 6;
    const int lr = l & 15, lk = l >> 4;

    const int bid = blockIdx.x;
    const int c  = bid & 7;
    const int e  = bid >> 3;
    const int cx = c % CHX, cy = c / CHX;
    const int nt = cx * RECT_N + e % RECT_N;
    const int mt = cy * RECT_M + e / RECT_N;
    const int m0 = mt * BM, n0 = nt * BN;
    const int wm = w >> 1, wn = w & 1;

    f32x4 acc[FM][FN] = {};

    // stage one K-tile (BK=64): A slabs s=w*FM+i (k32=s&1, mf=s>>1), B same
    auto stage = [&](int buf, int k0) {
        #pragma unroll
        for (int i = 0; i < FM; ++i) {
            int s = w * FM + i, k32 = s & 1, mf = s >> 1;
            __builtin_amdgcn_global_load_lds(
                GLB_AS(A + (size_t)(m0 + mf * 16 + lr) * K + k0 + k32 * 32 + lk * 8),
                LDS_AS(&Asm[buf][((k32 * MFRAG + mf) * 64 + l) * 8]), 16, 0, 0);
        }
        #pragma unroll
        for (int i = 0; i < FN; ++i) {
            int s = w * FN + i, k32 = s & 1, nf = s >> 1;
            __builtin_amdgcn_global_load_lds(
                GLB_AS(BT + (size_t)(n0 + nf * 16 + lr) * K + k0 + k32 * 32 + lk * 8),
                LDS_AS(&Bsm[buf][((k32 * NFRAG + nf) * 64 + l) * 8]), 16, 0, 0);
        }
    };

    stage(0, 0);
    if (K > 64) stage(1, 64);
    int cur = 0;
    for (int k0 = 0; k0 < K; k0 += 64) {
        if (k0 + 64 < K) {               // next tile in flight -> keep NL
            if constexpr (NL == 8)
                asm volatile("s_waitcnt vmcnt(8)" ::: "memory");
            else
                asm volatile("s_waitcnt vmcnt(4)" ::: "memory");
        } else {
            asm volatile("s_waitcnt vmcnt(0)" ::: "memory");
        }
        __builtin_amdgcn_s_barrier();
        __builtin_amdgcn_sched_barrier(0);
        s16x8 af[2][FM], bfv[2][FN];
        #pragma unroll
        for (int kk = 0; kk < 2; ++kk) {
            #pragma unroll
            for (int i = 0; i < FM; ++i)
                af[kk][i] = *(const s16x8*)
                    &Asm[cur][((kk * MFRAG + wm * FM + i) * 64 + l) * 8];
            #pragma unroll
            for (int j = 0; j < FN; ++j)
                bfv[kk][j] = *(const s16x8*)
                    &Bsm[cur][((kk * NFRAG + wn * FN + j) * 64 + l) * 8];
        }
        #pragma unroll
        for (int kk = 0; kk < 2; ++kk)
            #pragma unroll
            for (int i = 0; i < FM; ++i)
                #pragma unroll
                for (int j = 0; j < FN; ++j)
                    acc[i][j] = mfma16(af[kk][i], bfv[kk][j], acc[i][j]);
        __builtin_amdgcn_s_barrier();
        if (k0 + 128 < K) stage(cur, k0 + 128);
        cur ^= 1;
    }

    #pragma unroll
    for (int i = 0; i < FM; ++i) {
        int row = m0 + (wm * FM + i) * 16 + lk * 4;
        #pragma unroll
        for (int j = 0; j < FN; ++j) {
            int col = n0 + (wn * FN + j) * 16 + lr;
            if (GUARD_N && col >= Nreal) continue;
            float bv = bias[col];
            #pragma unroll
            for (int r = 0; r < 4; ++r) {
                float v = acc[i][j][r] + bv;
                if (HAS_ADD) v += add[(size_t)(row + r) * Nstride + col];
                if (OUT_BF16) {
                    Cb[(size_t)(row + r) * Nstride + col] = f2bf(v);
                    if (col >= DT_OFF)
                        dtb[(size_t)(row + r) * HEADS + (col - DT_OFF)] = v;
                } else {
                    C[(size_t)(row + r) * Nstride + col] = v;
                }
            }
        }
    }
}

// ================= SSD chunked scan (MFMA), LQ=32 =================
__global__ __launch_bounds__(256) void ssd_pass1(
    const unsigned short* __restrict__ zx, const float* __restrict__ dtbuf,
    const float* __restrict__ A_log, const float* __restrict__ dt_bias,
    unsigned short* __restrict__ Sbuf, float* __restrict__ Dk)
{
    __shared__ float w1s[LQ];
    __shared__ unsigned short xT[HEAD_DIM * LQ];  // [p][t ^ ((p&3)<<3)]
    __shared__ unsigned short BpT[STATE * LQ];    // [n][t ^ ((n&3)<<3)]
    int blk = blockIdx.x;
    int bh = blk >> 5, ck = blk & (NCH - 1);
    int b = bh >> 3, h = bh & 7;
    int tid = threadIdx.x;
    int l = tid & 63, w = tid >> 6;
    int lr = l & 15, lk = l >> 4;
    float a = -expf(A_log[h]);
    int t0 = ck * LQ;
    const unsigned short* zrow = zx + (size_t)(b * SEQ + t0) * PROJ_OUT;

    if (w == 0) {
        int tl = l & 31;
        float dtr = dtbuf[(size_t)(b * SEQ + t0 + tl) * HEADS + h] + dt_bias[h];
        float dtv = (dtr > 20.f) ? dtr : log1pf(expf(dtr));
        float c = dtv;
        #pragma unroll
        for (int off = 1; off < 32; off <<= 1) {
            float v = __shfl_up(c, off, 64);
            if ((l & 31) >= off) c += v;
        }
        float c31 = __shfl(c, 31, 64);
        if (l < 32) {
            w1s[l] = dtv * expf(a * (c31 - c));
            if (l == 31) Dk[bh * NCH + ck] = expf(a * c31);
        }
    }
    {   // xT staging: thread = p
        int p = tid;
        const unsigned short* xp = zrow + INNER + h * HEAD_DIM + p;
        int sw = (p & 3) << 3;
        #pragma unroll
        for (int tp = 0; tp < 16; ++tp) {
            unsigned int x0 = xp[(size_t)(2 * tp) * PROJ_OUT];
            unsigned int x1 = xp[(size_t)(2 * tp + 1) * PROJ_OUT];
            *(unsigned int*)&xT[p * LQ + ((2 * tp) ^ sw)] = x0 | (x1 << 16);
        }
    }
    __syncthreads();
    #pragma unroll
    for (int i = 0; i < 8; ++i) {
        int e = i * 256 + tid;
        int t = e >> 6, n = e & 63;
        float v = bf2f(zrow[(size_t)t * PROJ_OUT + 2 * INNER + n]) * w1s[t];
        BpT[n * LQ + (t ^ ((n & 3) << 3))] = f2bf(v);
    }
    __syncthreads();

    f32x4 acc[4][4] = {};
    {
        int krun = lk * 8;
        s16x8 bfr[4];
        #pragma unroll
        for (int j = 0; j < 4; ++j) {
            int n = j * 16 + lr;
            bfr[j] = *(const s16x8*)&BpT[n * LQ + (krun ^ ((n & 3) << 3))];
        }
        #pragma unroll
        for (int i = 0; i < 4; ++i) {
            int p = (w * 4 + i) * 16 + lr;
            s16x8 afr = *(const s16x8*)&xT[p * LQ + (krun ^ ((p & 3) << 3))];
            #pragma unroll
            for (int j = 0; j < 4; ++j)
                acc[i][j] = mfma16(afr, bfr[j], acc[i][j]);
        }
    }
    unsigned short* sp = Sbuf + ((size_t)bh * NCH + ck) * (STATE * HEAD_DIM);
    #pragma unroll
    for (int i = 0; i < 4; ++i) {
        int p = (w * 4 + i) * 16 + lk * 4;
        #pragma unroll
        for (int j = 0; j < 4; ++j) {
            int n = j * 16 + lr;
            #pragma unroll
            for (int r = 0; r < 4; ++r)
                sp[(size_t)(p + r) * STATE + n] = f2bf(acc[i][j][r]);
        }
    }
}

template<int NCHq>
__global__ __launch_bounds__(256) void scan_combine(
    unsigned short* __restrict__ Sbuf, const float* __restrict__ Dk)
{
    int bh = blockIdx.y;
    int e  = blockIdx.x * 256 + threadIdx.x;
    size_t base = (size_t)bh * NCHq * (STATE * HEAD_DIM) + e;
    float h = 0.f;
    #pragma unroll 8
    for (int k = 0; k < NCHq; ++k) {
        size_t idx = base + (size_t)k * (STATE * HEAD_DIM);
        float s = bf2f(Sbuf[idx]);
        Sbuf[idx] = f2bf(h);
        h = Dk[bh * NCHq + k] * h + s;
    }
}

__global__ __launch_bounds__(256) void ssd_pass2(
    const unsigned short* __restrict__ zx, const float* __restrict__ dtbuf,
    const float* __restrict__ A_log, const float* __restrict__ D_skip,
    const float* __restrict__ dt_bias,
    const unsigned short* __restrict__ Sbuf, unsigned short* __restrict__ yg)
{
    __shared__ float dts[LQ], cums[LQ];
    __shared__ unsigned short xT[HEAD_DIM * LQ];  // [p][s ^ ((p&3)<<3)]
    __shared__ unsigned short Cm[LQ * STATE];     // [t][n ^ ((t&7)<<3)]
    __shared__ unsigned short Cd[LQ * STATE];     // C * exp(a*cum_t)
    __shared__ unsigned short Bm[LQ * STATE];
    __shared__ unsigned short Pp[LQ * LQ];        // [t][s ^ ((t&3)<<3)]
    int blk = blockIdx.x;
    int bh = blk >> 5, ck = blk & (NCH - 1);
    int b = bh >> 3, h = bh & 7;
    int tid = threadIdx.x;
    int l = tid & 63, w = tid >> 6;
    int lr = l & 15, lk = l >> 4;
    float a = -expf(A_log[h]);
    float dsk = D_skip[h];
    int t0 = ck * LQ;
    const unsigned short* zrow = zx + (size_t)(b * SEQ + t0) * PROJ_OUT;

    if (w == 0) {
        int tl = l & 31;
        float dtr = dtbuf[(size_t)(b * SEQ + t0 + tl) * HEADS + h] + dt_bias[h];
        float dtv = (dtr > 20.f) ? dtr : log1pf(expf(dtr));
        float c = dtv;
        #pragma unroll
        for (int off = 1; off < 32; off <<= 1) {
            float v = __shfl_up(c, off, 64);
            if ((l & 31) >= off) c += v;
        }
        if (l < 32) { dts[l] = dtv; cums[l] = c; }
    }
    {   // xT staging
        int p = tid;
        const unsigned short* xp = zrow + INNER + h * HEAD_DIM + p;
        int sw = (p & 3) << 3;
        #pragma unroll
        for (int tp = 0; tp < 16; ++tp) {
            unsigned int x0 = xp[(size_t)(2 * tp) * PROJ_OUT];
            unsigned int x1 = xp[(size_t)(2 * tp + 1) * PROJ_OUT];
            *(unsigned int*)&xT[p * LQ + ((2 * tp) ^ sw)] = x0 | (x1 << 16);
        }
    }
    __syncthreads();
    #pragma unroll
    for (int i = 0; i < 8; ++i) {
        int e = i * 256 + tid;
        int t = e >> 6, n = e & 63;
        int sn = n ^ ((t & 7) << 3);
        unsigned short cv = zrow[(size_t)t * PROJ_OUT + 2 * INNER + STATE + n];
        Cm[t * STATE + sn] = cv;
        Cd[t * STATE + sn] = f2bf(bf2f(cv) * expf(a * cums[t]));
        Bm[t * STATE + sn] = zrow[(size_t)t * PROJ_OUT + 2 * INNER + n];
    }
    __syncthreads();

    const unsigned short* hbase = Sbuf + ((size_t)bh * NCH + ck) * (STATE * HEAD_DIM);
    s16x8 h0f[4][2];
    #pragma unroll
    for (int j = 0; j < 4; ++j) {
        int p = w * 64 + j * 16 + lr;
        #pragma unroll
        for (int kk = 0; kk < 2; ++kk)
            h0f[j][kk] = *(const s16x8*)&hbase[(size_t)p * STATE + kk * 32 + lk * 8];
    }

    // P-GEMM: wave w computes 16x16 subtile (t-tile = w>>1, s-tile = w&1), K=64(n)
    f32x4 pa = {};
    #pragma unroll
    for (int kk = 0; kk < 2; ++kk) {
        int krun = kk * 32 + lk * 8;
        int tA = (w >> 1) * 16 + lr;
        int sB = (w & 1) * 16 + lr;
        s16x8 afr = *(const s16x8*)&Cm[tA * STATE + (krun ^ ((tA & 7) << 3))];
        s16x8 bfr = *(const s16x8*)&Bm[sB * STATE + (krun ^ ((sB & 7) << 3))];
        pa = mfma16(afr, bfr, pa);
    }
    #pragma unroll
    for (int r = 0; r < 4; ++r) {
        int t = (w >> 1) * 16 + lk * 4 + r;
        int s = (w & 1) * 16 + lr;
        float sc = (s <= t) ? dts[s] * expf(a * (cums[t] - cums[s])) : 0.f;
        Pp[t * LQ + (s ^ ((t & 3) << 3))] = f2bf(pa[r] * sc);
    }
    __syncthreads();

    // Y-GEMM: wave w owns p-slice [64w,64w+64); Y = P'@x + Cd@h0
    f32x4 ya[2][4] = {};
    {
        int krun = lk * 8;
        s16x8 bfr[4];
        #pragma unroll
        for (int j = 0; j < 4; ++j) {
            int p = w * 64 + j * 16 + lr;
            bfr[j] = *(const s16x8*)&xT[p * LQ + (krun ^ ((p & 3) << 3))];
        }
        #pragma unroll
        for (int i = 0; i < 2; ++i) {
            int t = i * 16 + lr;
            s16x8 afr = *(const s16x8*)&Pp[t * LQ + (krun ^ ((t & 3) << 3))];
            #pragma unroll
            for (int j = 0; j < 4; ++j)
                ya[i][j] = mfma16(afr, bfr[j], ya[i][j]);
        }
    }
    #pragma unroll
    for (int kk = 0; kk < 2; ++kk) {
        int krun = kk * 32 + lk * 8;
        #pragma unroll
        for (int i = 0; i < 2; ++i) {
            int t = i * 16 + lr;
            s16x8 afr = *(const s16x8*)&Cd[t * STATE + (krun ^ ((t & 7) << 3))];
            #pragma unroll
            for (int j = 0; j < 4; ++j)
                ya[i][j] = mfma16(afr, h0f[j][kk], ya[i][j]);
        }
    }

    #pragma unroll
    for (int i = 0; i < 2; ++i) {
        #pragma unroll
        for (int r = 0; r < 4; ++r) {
            int t = i * 16 + lk * 4 + r;
            #pragma unroll
            for (int j = 0; j < 4; ++j) {
                int p = w * 64 + j * 16 + lr;
                float xv = bf2f(xT[p * LQ + (t ^ ((p & 3) << 3))]);
                float z  = bf2f(zrow[(size_t)t * PROJ_OUT + h * HEAD_DIM + p]);
                float y = ya[i][j][r] + dsk * xv;
                float gate = z / (1.f + expf(-z));
                yg[(size_t)(b * SEQ + t0 + t) * INNER + h * HEAD_DIM + p] = f2bf(y * gate);
            }
        }
    }
}

// ---------------- fallback serial scan (ws too small) ----------------
__global__ __launch_bounds__(256) void scan_serial(
    const unsigned short* __restrict__ zx, const float* __restrict__ dtbuf,
    const float* __restrict__ A_log, const float* __restrict__ D_skip,
    const float* __restrict__ dt_bias,
    unsigned short* __restrict__ yg)
{
    int bh = blockIdx.x;
    int b  = bh >> 3, h = bh & 7;
    int p  = threadIdx.x;
    float a   = -expf(A_log[h]);
    float dsk = D_skip[h];
    float dtb = dt_bias[h];

    float hs[STATE];
    #pragma unroll
    for (int n = 0; n < STATE; ++n) hs[n] = 0.f;

    for (int t = 0; t < SEQ; ++t) {
        const unsigned short* row = zx + (size_t)(b * SEQ + t) * PROJ_OUT;
        float dtr = dtbuf[(size_t)(b * SEQ + t) * HEADS + h] + dtb;
        float dt  = (dtr > 20.f) ? dtr : log1pf(expf(dtr));
        float dec = expf(dt * a);
        float x   = bf2f(row[INNER + h * HEAD_DIM + p]);
        float z   = bf2f(row[h * HEAD_DIM + p]);
        float dtx = dt * x;
        #pragma unroll
        for (int n = 0; n < STATE; ++n)
            hs[n] = dec * hs[n] + dtx * bf2f(row[2 * INNER + n]);
        float y0 = 0.f;
        #pragma unroll
        for (int n = 0; n < STATE; ++n)
            y0 += hs[n] * bf2f(row[2 * INNER + STATE + n]);
        float y = y0 + dsk * x;
        float gate = z / (1.f + expf(-z));
        yg[(size_t)(b * SEQ + t) * INNER + h * HEAD_DIM + p] = f2bf(y * gate);
    }
}

extern "C" void kernel_launch(void* const* d_in, const int* in_sizes, int n_in,
                              void* d_out, int out_size, void* d_ws, size_t ws_size,
                              hipStream_t stream) {
    const float* input  = (const float*)d_in[0];
    const float* gamma  = (const float*)d_in[1];
    const float* beta   = (const float*)d_in[2];
    const float* W_in   = (const float*)d_in[3];
    const float* b_in   = (const float*)d_in[4];
    const float* A_log  = (const float*)d_in[5];
    const float* D_skip = (const float*)d_in[6];
    const float* dt_b   = (const float*)d_in[7];
    const float* W_out  = (const float*)d_in[8];
    const float* b_out  = (const float*)d_in[9];
    float* out = (float*)d_out;

    char* ws = (char*)d_ws;
    size_t off = 0;
    unsigned short* normed_bf = (unsigned short*)(ws + off); off += (size_t)NROWS * D_MODEL * 2;
    unsigned short* zx        = (unsigned short*)(ws + off); off += (size_t)NROWS * PROJ_OUT * 2;
    float*          dtbuf     = (float*)(ws + off);          off += (size_t)NROWS * HEADS * 4;
    unsigned short* yg        = (unsigned short*)(ws + off); off += (size_t)NROWS * INNER * 2;
    unsigned short* WT        = (unsigned short*)(ws + off); off += (size_t)NPAD * D_MODEL * 2;
    unsigned short* WoT       = (unsigned short*)(ws + off); off += (size_t)D_MODEL * INNER * 2;
    unsigned short* Sbuf      = (unsigned short*)(ws + off); off += (size_t)BH * NCH * STATE * HEAD_DIM * 2;
    off = (off + 255) & ~(size_t)255;
    float*          Dk        = (float*)(ws + off);          off += (size_t)BH * NCH * 4;
    bool ssd = (off <= ws_size);

    // fused prep
    constexpr int T1 = (NPAD / 32) * (D_MODEL / 32);
    constexpr int T2 = (D_MODEL / 32) * (INNER / 32);
    constexpr int T3 = NROWS / 2;
    prep_kernel<<<T1 + T2 + T3, 256, 0, stream>>>(
        input, gamma, beta, W_in, W_out, normed_bf, WT, WoT);

    // GEMM1: 128x128 tiles, BK=64, 544 blocks, XCD rect 17n x 4m
    gemm_bf16<128, 128, 17, 4, 2, false, true, true><<<544, 256, 0, stream>>>(
        normed_bf, WT, b_in, nullptr, nullptr, zx, dtbuf, PROJ_OUT, PROJ_OUT, D_MODEL);

    if (ssd) {
        ssd_pass1<<<BH * NCH, 256, 0, stream>>>(zx, dtbuf, A_log, dt_b, Sbuf, Dk);
        dim3 gc(STATE * HEAD_DIM / 256, BH);
        scan_combine<NCH><<<gc, 256, 0, stream>>>(Sbuf, Dk);
        ssd_pass2<<<BH * NCH, 256, 0, stream>>>(zx, dtbuf, A_log, D_skip, dt_b, Sbuf, yg);
    } else {
        scan_serial<<<BH, 256, 0, stream>>>(zx, dtbuf, A_log, D_skip, dt_b, yg);
    }

    // GEMM2: 64x64 tiles, BK=64, 512 blocks, XCD rect 16n x 4m
    gemm_bf16<64, 64, 16, 4, 1, true, false, false><<<512, 256, 0, stream>>>(
        yg, WoT, b_out, input, out, nullptr, nullptr, D_MODEL, D_MODEL, INNER);
}

// Round 18
// 130.826 us; speedup vs baseline: 1.0521x; 1.0521x over previous
//
#include <hip/hip_runtime.h>
#include <math.h>

#define D_MODEL 1024
#define STATE 64
#define HEADS 8
#define INNER 2048
#define HEAD_DIM 256
#define PROJ_OUT 4232   // 2*INNER + 2*STATE + HEADS
#define DT_OFF  4224    // 2*INNER + 2*STATE
#define NPAD 4352       // 34*128
#define BATCH 2
#define SEQ 1024
#define NROWS (BATCH*SEQ)
#define EPS 1e-5f
#define BH (BATCH * HEADS)      // 16
#define LQ 32                   // SSD chunk length
#define NCH (SEQ / LQ)          // 32 chunks

typedef short s16x8 __attribute__((ext_vector_type(8)));
typedef float f32x4 __attribute__((ext_vector_type(4)));

#define LDS_AS(p) ((__attribute__((address_space(3))) void*)(p))
#define GLB_AS(p) ((const __attribute__((address_space(1))) void*)(p))

__device__ inline unsigned short f2bf(float f) {
    unsigned int u = __float_as_uint(f);
    unsigned int r = (u + 0x7fffu + ((u >> 16) & 1u)) >> 16;
    return (unsigned short)r;
}
__device__ inline float bf2f(unsigned short s) {
    return __uint_as_float(((unsigned int)s) << 16);
}
__device__ inline f32x4 mfma16(s16x8 a, s16x8 b, f32x4 c) {
    return __builtin_amdgcn_mfma_f32_16x16x32_bf16(a, b, c, 0, 0, 0);
}

// ====== prep: fused {W_in transpose, W_out transpose, LayerNorm} ======
__global__ __launch_bounds__(256) void prep_kernel(
    const float* __restrict__ x, const float* __restrict__ gamma,
    const float* __restrict__ beta,
    const float* __restrict__ W_in, const float* __restrict__ W_out,
    unsigned short* __restrict__ normed, unsigned short* __restrict__ WT,
    unsigned short* __restrict__ WoT)
{
    constexpr int T1 = (NPAD / 32) * (D_MODEL / 32);   // 4352
    constexpr int T2 = (D_MODEL / 32) * (INNER / 32);  // 2048
    __shared__ float tile[32][33];
    __shared__ float ls[4], lq[4];
    const int bid = blockIdx.x;
    const int tid = threadIdx.x;

    if (bid < T1 + T2) {
        const float* in;
        unsigned short* out;
        int R, C, bx, by;
        if (bid < T1) {
            in = W_in; out = WT; R = D_MODEL; C = PROJ_OUT;
            bx = bid % (NPAD / 32); by = bid / (NPAD / 32);
        } else {
            int t = bid - T1;
            in = W_out; out = WoT; R = INNER; C = D_MODEL;
            bx = t % (D_MODEL / 32); by = t / (D_MODEL / 32);
        }
        int c0 = bx * 32, r0 = by * 32;
        int tx = tid & 31, ty = tid >> 5;
        #pragma unroll
        for (int i = 0; i < 4; ++i) {
            int r = ty + i * 8;
            int gc = c0 + tx;
            tile[r][tx] = (gc < C) ? in[(size_t)(r0 + r) * C + gc] : 0.f;
        }
        __syncthreads();
        #pragma unroll
        for (int i = 0; i < 4; ++i) {
            int oc = ty + i * 8;
            out[(size_t)(c0 + oc) * R + r0 + tx] = f2bf(tile[tx][oc]);
        }
    } else {
        int t = bid - T1 - T2;
        int wave = tid >> 6, lane = tid & 63;
        #pragma unroll
        for (int rr = 0; rr < 2; ++rr) {
            int row = t * 2 + rr;
            const float4* xr = (const float4*)(x + (size_t)row * D_MODEL);
            float4 v = xr[tid];
            float s  = v.x + v.y + v.z + v.w;
            float sq = v.x*v.x + v.y*v.y + v.z*v.z + v.w*v.w;
            #pragma unroll
            for (int off = 32; off > 0; off >>= 1) {
                s  += __shfl_down(s,  off, 64);
                sq += __shfl_down(sq, off, 64);
            }
            if (lane == 0) { ls[wave] = s; lq[wave] = sq; }
            __syncthreads();
            s  = ls[0] + ls[1] + ls[2] + ls[3];
            sq = lq[0] + lq[1] + lq[2] + lq[3];
            float mu  = s * (1.f / D_MODEL);
            float var = sq * (1.f / D_MODEL) - mu * mu;
            float rs  = rsqrtf(var + EPS);
            float4 g  = ((const float4*)gamma)[tid];
            float4 bb = ((const float4*)beta)[tid];
            ushort4 o;
            o.x = f2bf((v.x - mu) * rs * g.x + bb.x);
            o.y = f2bf((v.y - mu) * rs * g.y + bb.y);
            o.z = f2bf((v.z - mu) * rs * g.z + bb.z);
            o.w = f2bf((v.w - mu) * rs * g.w + bb.w);
            ((ushort4*)(normed + (size_t)row * D_MODEL))[tid] = o;
            __syncthreads();
        }
    }
}

// ---- bf16 MFMA GEMM: 3-deep ring buffer + counted vmcnt + XCD swizzle ----
template<int BM, int BN, int RECT_N, int RECT_M, int CHX,
         bool HAS_ADD, bool GUARD_N, bool OUT_BF16>
__global__ __launch_bounds__(256) void gemm_bf16(
    const unsigned short* __restrict__ A, const unsigned short* __restrict__ BT,
    const float* __restrict__ bias, const float* __restrict__ add,
    float* __restrict__ C, unsigned short* __restrict__ Cb,
    float* __restrict__ dtb, int Nreal, int Nstride, int K)
{
    constexpr int FM = BM / 32;
    constexpr int FN = BN / 32;
    constexpr int NL = BM / 64 + BN / 64;
    __shared__ unsigned short Asm[3][BM * 32];
    __shared__ unsigned short Bsm[3][BN * 32];
    const int tid = threadIdx.x;
    const int l = tid & 63, w = tid >> 6;
    const int lr = l & 15, lk = l >> 4;

    const int bid = blockIdx.x;
    const int c  = bid & 7;
    const int e  = bid >> 3;
    const int cx = c % CHX, cy = c / CHX;
    const int nt = cx * RECT_N + e % RECT_N;
    const int mt = cy * RECT_M + e / RECT_N;
    const int m0 = mt * BM, n0 = nt * BN;
    const int wm = w >> 1, wn = w & 1;

    f32x4 acc[FM][FN] = {};

    const unsigned short* Abase = A  + (size_t)(m0 + lr) * K + lk * 8;
    const unsigned short* Bbase = BT + (size_t)(n0 + lr) * K + lk * 8;

    auto stage = [&](int buf, int k0) {
        #pragma unroll
        for (int i = 0; i < BM / 64; ++i) {
            int mb = w + 4 * i;
            __builtin_amdgcn_global_load_lds(
                GLB_AS(Abase + (size_t)mb * 16 * K + k0),
                LDS_AS(&Asm[buf][mb * 512]), 16, 0, 0);
        }
        #pragma unroll
        for (int i = 0; i < BN / 64; ++i) {
            int nb = w + 4 * i;
            __builtin_amdgcn_global_load_lds(
                GLB_AS(Bbase + (size_t)nb * 16 * K + k0),
                LDS_AS(&Bsm[buf][nb * 512]), 16, 0, 0);
        }
    };

    stage(0, 0);
    stage(1, 32);
    stage(2, 64);
    int cur = 0;
    for (int k0 = 0; k0 < K; k0 += 32) {
        if (k0 + 96 <= K) {
            if constexpr (NL == 4)
                asm volatile("s_waitcnt vmcnt(8)" ::: "memory");
            else
                asm volatile("s_waitcnt vmcnt(4)" ::: "memory");
        } else if (k0 + 64 <= K) {
            if constexpr (NL == 4)
                asm volatile("s_waitcnt vmcnt(4)" ::: "memory");
            else
                asm volatile("s_waitcnt vmcnt(2)" ::: "memory");
        } else {
            asm volatile("s_waitcnt vmcnt(0)" ::: "memory");
        }
        __builtin_amdgcn_s_barrier();
        __builtin_amdgcn_sched_barrier(0);
        s16x8 af[FM], bfv[FN];
        #pragma unroll
        for (int i = 0; i < FM; ++i)
            af[i] = *(const s16x8*)&Asm[cur][((wm * FM + i) * 64 + l) * 8];
        #pragma unroll
        for (int j = 0; j < FN; ++j)
            bfv[j] = *(const s16x8*)&Bsm[cur][((wn * FN + j) * 64 + l) * 8];
        #pragma unroll
        for (int i = 0; i < FM; ++i)
            #pragma unroll
            for (int j = 0; j < FN; ++j)
                acc[i][j] = mfma16(af[i], bfv[j], acc[i][j]);
        __builtin_amdgcn_s_barrier();
        if (k0 + 128 <= K) stage(cur, k0 + 96);
        cur = (cur == 2) ? 0 : cur + 1;
    }

    #pragma unroll
    for (int i = 0; i < FM; ++i) {
        int row = m0 + (wm * FM + i) * 16 + lk * 4;
        #pragma unroll
        for (int j = 0; j < FN; ++j) {
            int col = n0 + (wn * FN + j) * 16 + lr;
            if (GUARD_N && col >= Nreal) continue;
            float bv = bias[col];
            #pragma unroll
            for (int r = 0; r < 4; ++r) {
                float v = acc[i][j][r] + bv;
                if (HAS_ADD) v += add[(size_t)(row + r) * Nstride + col];
                if (OUT_BF16) {
                    Cb[(size_t)(row + r) * Nstride + col] = f2bf(v);
                    if (col >= DT_OFF)
                        dtb[(size_t)(row + r) * HEADS + (col - DT_OFF)] = v;
                } else {
                    C[(size_t)(row + r) * Nstride + col] = v;
                }
            }
        }
    }
}

// ================= SSD chunked scan (MFMA), LQ=32 =================
__global__ __launch_bounds__(256) void ssd_pass1(
    const unsigned short* __restrict__ zx, const float* __restrict__ dtbuf,
    const float* __restrict__ A_log, const float* __restrict__ dt_bias,
    unsigned short* __restrict__ Sbuf, float* __restrict__ Dk)
{
    __shared__ float w1s[LQ];
    __shared__ unsigned short xT[HEAD_DIM * LQ];  // [p][t ^ ((p&3)<<3)]
    __shared__ unsigned short BpT[STATE * LQ];    // [n][t ^ ((n&3)<<3)]
    int blk = blockIdx.x;
    int bh = blk >> 5, ck = blk & (NCH - 1);
    int b = bh >> 3, h = bh & 7;
    int tid = threadIdx.x;
    int l = tid & 63, w = tid >> 6;
    int lr = l & 15, lk = l >> 4;
    float a = -expf(A_log[h]);
    int t0 = ck * LQ;
    const unsigned short* zrow = zx + (size_t)(b * SEQ + t0) * PROJ_OUT;

    if (w == 0) {
        int tl = l & 31;
        float dtr = dtbuf[(size_t)(b * SEQ + t0 + tl) * HEADS + h] + dt_bias[h];
        float dtv = (dtr > 20.f) ? dtr : log1pf(expf(dtr));
        float c = dtv;
        #pragma unroll
        for (int off = 1; off < 32; off <<= 1) {
            float v = __shfl_up(c, off, 64);
            if ((l & 31) >= off) c += v;
        }
        float c31 = __shfl(c, 31, 64);
        if (l < 32) {
            w1s[l] = dtv * expf(a * (c31 - c));
            if (l == 31) Dk[bh * NCH + ck] = expf(a * c31);
        }
    }
    {   // xT staging: thread = p
        int p = tid;
        const unsigned short* xp = zrow + INNER + h * HEAD_DIM + p;
        int sw = (p & 3) << 3;
        #pragma unroll
        for (int tp = 0; tp < 16; ++tp) {
            unsigned int x0 = xp[(size_t)(2 * tp) * PROJ_OUT];
            unsigned int x1 = xp[(size_t)(2 * tp + 1) * PROJ_OUT];
            *(unsigned int*)&xT[p * LQ + ((2 * tp) ^ sw)] = x0 | (x1 << 16);
        }
    }
    __syncthreads();
    #pragma unroll
    for (int i = 0; i < 8; ++i) {
        int e = i * 256 + tid;
        int t = e >> 6, n = e & 63;
        float v = bf2f(zrow[(size_t)t * PROJ_OUT + 2 * INNER + n]) * w1s[t];
        BpT[n * LQ + (t ^ ((n & 3) << 3))] = f2bf(v);
    }
    __syncthreads();

    f32x4 acc[4][4] = {};
    {
        int krun = lk * 8;
        s16x8 bfr[4];
        #pragma unroll
        for (int j = 0; j < 4; ++j) {
            int n = j * 16 + lr;
            bfr[j] = *(const s16x8*)&BpT[n * LQ + (krun ^ ((n & 3) << 3))];
        }
        #pragma unroll
        for (int i = 0; i < 4; ++i) {
            int p = (w * 4 + i) * 16 + lr;
            s16x8 afr = *(const s16x8*)&xT[p * LQ + (krun ^ ((p & 3) << 3))];
            #pragma unroll
            for (int j = 0; j < 4; ++j)
                acc[i][j] = mfma16(afr, bfr[j], acc[i][j]);
        }
    }
    unsigned short* sp = Sbuf + ((size_t)bh * NCH + ck) * (STATE * HEAD_DIM);
    #pragma unroll
    for (int i = 0; i < 4; ++i) {
        int p = (w * 4 + i) * 16 + lk * 4;
        #pragma unroll
        for (int j = 0; j < 4; ++j) {
            int n = j * 16 + lr;
            #pragma unroll
            for (int r = 0; r < 4; ++r)
                sp[(size_t)(p + r) * STATE + n] = f2bf(acc[i][j][r]);
        }
    }
}

template<int NCHq>
__global__ __launch_bounds__(256) void scan_combine(
    unsigned short* __restrict__ Sbuf, const float* __restrict__ Dk)
{
    int bh = blockIdx.y;
    int e  = blockIdx.x * 256 + threadIdx.x;
    size_t base = (size_t)bh * NCHq * (STATE * HEAD_DIM) + e;
    float h = 0.f;
    #pragma unroll 8
    for (int k = 0; k < NCHq; ++k) {
        size_t idx = base + (size_t)k * (STATE * HEAD_DIM);
        float s = bf2f(Sbuf[idx]);
        Sbuf[idx] = f2bf(h);
        h = Dk[bh * NCHq + k] * h + s;
    }
}

__global__ __launch_bounds__(256) void ssd_pass2(
    const unsigned short* __restrict__ zx, const float* __restrict__ dtbuf,
    const float* __restrict__ A_log, const float* __restrict__ D_skip,
    const float* __restrict__ dt_bias,
    const unsigned short* __restrict__ Sbuf, unsigned short* __restrict__ yg)
{
    __shared__ float dts[LQ], cums[LQ];
    __shared__ unsigned short xT[HEAD_DIM * LQ];  // [p][s ^ ((p&3)<<3)]
    __shared__ unsigned short Cm[LQ * STATE];     // [t][n ^ ((t&7)<<3)]
    __shared__ unsigned short Cd[LQ * STATE];     // C * exp(a*cum_t)
    __shared__ unsigned short Bm[LQ * STATE];
    __shared__ unsigned short Pp[LQ * LQ];        // [t][s ^ ((t&3)<<3)]
    int blk = blockIdx.x;
    int bh = blk >> 5, ck = blk & (NCH - 1);
    int b = bh >> 3, h = bh & 7;
    int tid = threadIdx.x;
    int l = tid & 63, w = tid >> 6;
    int lr = l & 15, lk = l >> 4;
    float a = -expf(A_log[h]);
    float dsk = D_skip[h];
    int t0 = ck * LQ;
    const unsigned short* zrow = zx + (size_t)(b * SEQ + t0) * PROJ_OUT;

    if (w == 0) {
        int tl = l & 31;
        float dtr = dtbuf[(size_t)(b * SEQ + t0 + tl) * HEADS + h] + dt_bias[h];
        float dtv = (dtr > 20.f) ? dtr : log1pf(expf(dtr));
        float c = dtv;
        #pragma unroll
        for (int off = 1; off < 32; off <<= 1) {
            float v = __shfl_up(c, off, 64);
            if ((l & 31) >= off) c += v;
        }
        if (l < 32) { dts[l] = dtv; cums[l] = c; }
    }
    {   // xT staging
        int p = tid;
        const unsigned short* xp = zrow + INNER + h * HEAD_DIM + p;
        int sw = (p & 3) << 3;
        #pragma unroll
        for (int tp = 0; tp < 16; ++tp) {
            unsigned int x0 = xp[(size_t)(2 * tp) * PROJ_OUT];
            unsigned int x1 = xp[(size_t)(2 * tp + 1) * PROJ_OUT];
            *(unsigned int*)&xT[p * LQ + ((2 * tp) ^ sw)] = x0 | (x1 << 16);
        }
    }
    __syncthreads();
    #pragma unroll
    for (int i = 0; i < 8; ++i) {
        int e = i * 256 + tid;
        int t = e >> 6, n = e & 63;
        int sn = n ^ ((t & 7) << 3);
        unsigned short cv = zrow[(size_t)t * PROJ_OUT + 2 * INNER + STATE + n];
        Cm[t * STATE + sn] = cv;
        Cd[t * STATE + sn] = f2bf(bf2f(cv) * expf(a * cums[t]));
        Bm[t * STATE + sn] = zrow[(size_t)t * PROJ_OUT + 2 * INNER + n];
    }
    __syncthreads();

    const unsigned short* hbase = Sbuf + ((size_t)bh * NCH + ck) * (STATE * HEAD_DIM);
    s16x8 h0f[4][2];
    #pragma unroll
    for (int j = 0; j < 4; ++j) {
        int p = w * 64 + j * 16 + lr;
        #pragma unroll
        for (int kk = 0; kk < 2; ++kk)
            h0f[j][kk] = *(const s16x8*)&hbase[(size_t)p * STATE + kk * 32 + lk * 8];
    }

    // P-GEMM: wave w computes 16x16 subtile (t-tile = w>>1, s-tile = w&1), K=64(n)
    f32x4 pa = {};
    #pragma unroll
    for (int kk = 0; kk < 2; ++kk) {
        int krun = kk * 32 + lk * 8;
        int tA = (w >> 1) * 16 + lr;
        int sB = (w & 1) * 16 + lr;
        s16x8 afr = *(const s16x8*)&Cm[tA * STATE + (krun ^ ((tA & 7) << 3))];
        s16x8 bfr = *(const s16x8*)&Bm[sB * STATE + (krun ^ ((sB & 7) << 3))];
        pa = mfma16(afr, bfr, pa);
    }
    #pragma unroll
    for (int r = 0; r < 4; ++r) {
        int t = (w >> 1) * 16 + lk * 4 + r;
        int s = (w & 1) * 16 + lr;
        float sc = (s <= t) ? dts[s] * expf(a * (cums[t] - cums[s])) : 0.f;
        Pp[t * LQ + (s ^ ((t & 3) << 3))] = f2bf(pa[r] * sc);
    }
    __syncthreads();

    // Y-GEMM: wave w owns p-slice [64w,64w+64); Y = P'@x + Cd@h0
    f32x4 ya[2][4] = {};
    {
        int krun = lk * 8;
        s16x8 bfr[4];
        #pragma unroll
        for (int j = 0; j < 4; ++j) {
            int p = w * 64 + j * 16 + lr;
            bfr[j] = *(const s16x8*)&xT[p * LQ + (krun ^ ((p & 3) << 3))];
        }
        #pragma unroll
        for (int i = 0; i < 2; ++i) {
            int t = i * 16 + lr;
            s16x8 afr = *(const s16x8*)&Pp[t * LQ + (krun ^ ((t & 3) << 3))];
            #pragma unroll
            for (int j = 0; j < 4; ++j)
                ya[i][j] = mfma16(afr, bfr[j], ya[i][j]);
        }
    }
    #pragma unroll
    for (int kk = 0; kk < 2; ++kk) {
        int krun = kk * 32 + lk * 8;
        #pragma unroll
        for (int i = 0; i < 2; ++i) {
            int t = i * 16 + lr;
            s16x8 afr = *(const s16x8*)&Cd[t * STATE + (krun ^ ((t & 7) << 3))];
            #pragma unroll
            for (int j = 0; j < 4; ++j)
                ya[i][j] = mfma16(afr, h0f[j][kk], ya[i][j]);
        }
    }

    #pragma unroll
    for (int i = 0; i < 2; ++i) {
        #pragma unroll
        for (int r = 0; r < 4; ++r) {
            int t = i * 16 + lk * 4 + r;
            #pragma unroll
            for (int j = 0; j < 4; ++j) {
                int p = w * 64 + j * 16 + lr;
                float xv = bf2f(xT[p * LQ + (t ^ ((p & 3) << 3))]);
                float z  = bf2f(zrow[(size_t)t * PROJ_OUT + h * HEAD_DIM + p]);
                float y = ya[i][j][r] + dsk * xv;
                float gate = z / (1.f + expf(-z));
                yg[(size_t)(b * SEQ + t0 + t) * INNER + h * HEAD_DIM + p] = f2bf(y * gate);
            }
        }
    }
}

// ---------------- fallback serial scan (ws too small) ----------------
__global__ __launch_bounds__(256) void scan_serial(
    const unsigned short* __restrict__ zx, const float* __restrict__ dtbuf,
    const float* __restrict__ A_log, const float* __restrict__ D_skip,
    const float* __restrict__ dt_bias,
    unsigned short* __restrict__ yg)
{
    int bh = blockIdx.x;
    int b  = bh >> 3, h = bh & 7;
    int p  = threadIdx.x;
    float a   = -expf(A_log[h]);
    float dsk = D_skip[h];
    float dtb = dt_bias[h];

    float hs[STATE];
    #pragma unroll
    for (int n = 0; n < STATE; ++n) hs[n] = 0.f;

    for (int t = 0; t < SEQ; ++t) {
        const unsigned short* row = zx + (size_t)(b * SEQ + t) * PROJ_OUT;
        float dtr = dtbuf[(size_t)(b * SEQ + t) * HEADS + h] + dtb;
        float dt  = (dtr > 20.f) ? dtr : log1pf(expf(dtr));
        float dec = expf(dt * a);
        float x   = bf2f(row[INNER + h * HEAD_DIM + p]);
        float z   = bf2f(row[h * HEAD_DIM + p]);
        float dtx = dt * x;
        #pragma unroll
        for (int n = 0; n < STATE; ++n)
            hs[n] = dec * hs[n] + dtx * bf2f(row[2 * INNER + n]);
        float y0 = 0.f;
        #pragma unroll
        for (int n = 0; n < STATE; ++n)
            y0 += hs[n] * bf2f(row[2 * INNER + STATE + n]);
        float y = y0 + dsk * x;
        float gate = z / (1.f + expf(-z));
        yg[(size_t)(b * SEQ + t) * INNER + h * HEAD_DIM + p] = f2bf(y * gate);
    }
}

extern "C" void kernel_launch(void* const* d_in, const int* in_sizes, int n_in,
                              void* d_out, int out_size, void* d_ws, size_t ws_size,
                              hipStream_t stream) {
    const float* input  = (const float*)d_in[0];
    const float* gamma  = (const float*)d_in[1];
    const float* beta   = (const float*)d_in[2];
    const float* W_in   = (const float*)d_in[3];
    const float* b_in   = (const float*)d_in[4];
    const float* A_log  = (const float*)d_in[5];
    const float* D_skip = (const float*)d_in[6];
    const float* dt_b   = (const float*)d_in[7];
    const float* W_out  = (const float*)d_in[8];
    const float* b_out  = (const float*)d_in[9];
    float* out = (float*)d_out;

    char* ws = (char*)d_ws;
    size_t off = 0;
    unsigned short* normed_bf = (unsigned short*)(ws + off); off += (size_t)NROWS * D_MODEL * 2;
    unsigned short* zx        = (unsigned short*)(ws + off); off += (size_t)NROWS * PROJ_OUT * 2;
    float*          dtbuf     = (float*)(ws + off);          off += (size_t)NROWS * HEADS * 4;
    unsigned short* yg        = (unsigned short*)(ws + off); off += (size_t)NROWS * INNER * 2;
    unsigned short* WT        = (unsigned short*)(ws + off); off += (size_t)NPAD * D_MODEL * 2;
    unsigned short* WoT       = (unsigned short*)(ws + off); off += (size_t)D_MODEL * INNER * 2;
    unsigned short* Sbuf      = (unsigned short*)(ws + off); off += (size_t)BH * NCH * STATE * HEAD_DIM * 2;
    off = (off + 255) & ~(size_t)255;
    float*          Dk        = (float*)(ws + off);          off += (size_t)BH * NCH * 4;
    bool ssd = (off <= ws_size);

    // fused prep
    constexpr int T1 = (NPAD / 32) * (D_MODEL / 32);
    constexpr int T2 = (D_MODEL / 32) * (INNER / 32);
    constexpr int T3 = NROWS / 2;
    prep_kernel<<<T1 + T2 + T3, 256, 0, stream>>>(
        input, gamma, beta, W_in, W_out, normed_bf, WT, WoT);

    // GEMM1: 128x128 tiles, 544 blocks, XCD rect 17n x 4m, 3-deep ring
    gemm_bf16<128, 128, 17, 4, 2, false, true, true><<<544, 256, 0, stream>>>(
        normed_bf, WT, b_in, nullptr, nullptr, zx, dtbuf, PROJ_OUT, PROJ_OUT, D_MODEL);

    if (ssd) {
        ssd_pass1<<<BH * NCH, 256, 0, stream>>>(zx, dtbuf, A_log, dt_b, Sbuf, Dk);
        dim3 gc(STATE * HEAD_DIM / 256, BH);
        scan_combine<NCH><<<gc, 256, 0, stream>>>(Sbuf, Dk);
        ssd_pass2<<<BH * NCH, 256, 0, stream>>>(zx, dtbuf, A_log, D_skip, dt_b, Sbuf, yg);
    } else {
        scan_serial<<<BH, 256, 0, stream>>>(zx, dtbuf, A_log, D_skip, dt_b, yg);
    }

    // GEMM2: 64x64 tiles, 512 blocks, XCD rect 16n x 4m, 3-deep ring
    gemm_bf16<64, 64, 16, 4, 1, true, false, false><<<512, 256, 0, stream>>>(
        yg, WoT, b_out, input, out, nullptr, nullptr, D_MODEL, D_MODEL, INNER);
}